// Round 8
// baseline (337.258 us; speedup 1.0000x reference)
//
#include <hip/hip_runtime.h>
#include <math.h>

#define BN 4
#define NN 2048
#define DD 256
#define EPSF 1e-5f

typedef __attribute__((ext_vector_type(8))) short bf16x8;
typedef __attribute__((ext_vector_type(4))) float f32x4;

// ---- output layout (float offsets) ----
constexpr size_t OFF_EST = 0;                                  // (B,2,N,D)
constexpr size_t OFF_OUT = (size_t)BN * 2 * NN * DD;           // (B,2,N,D)
constexpr size_t OFF_QIJ = OFF_OUT + (size_t)BN * 2 * NN * DD; // (B,2,N,N)
constexpr size_t OFF_VV  = OFF_QIJ + (size_t)BN * 2 * NN * NN; // (1,2,N,D)
constexpr size_t OFF_UV  = OFF_VV + (size_t)2 * NN * DD;       // (B,2,N,D)
constexpr size_t OFF_LH  = OFF_UV + (size_t)BN * 2 * NN * DD;  // (2,D,1)

// ---- scratch regions (Q_ij imaginary channels; zeroed before return) ----
constexpr size_t SCR_B0   = OFF_QIJ + (size_t)NN * NN;
constexpr size_t U_Q16    = 0;
constexpr size_t U_K16    = (size_t)BN * NN * DD;
constexpr size_t U_VT16   = 2 * (size_t)BN * NN * DD;
constexpr size_t SCR_QN   = SCR_B0 + 3 * (size_t)BN * NN * DD / 2;
constexpr size_t SCR_KN   = SCR_QN + (size_t)BN * NN;
constexpr size_t SCR_L    = SCR_KN + (size_t)BN * NN;
constexpr size_t SCR_SC   = SCR_L + (size_t)BN * NN;   // [tau2, s, ga_bar, om_bar]
constexpr size_t SCR_W16P = SCR_SC + 16;
constexpr size_t SCR_E16F = OFF_QIJ + 3 * (size_t)NN * NN;
constexpr size_t U_PART   = (size_t)BN * NN * 512;
constexpr size_t SCR_Z16F = OFF_QIJ + 5 * (size_t)NN * NN;
constexpr size_t SCR_Z16VF = OFF_QIJ + 7 * (size_t)NN * NN;
constexpr size_t U_W16    = (size_t)BN * NN * 512;
constexpr size_t W16_PER_B = 136 * 16384;

__device__ __forceinline__ short f2bf(float x) {
    union { float f; unsigned u; } v; v.f = x;
    unsigned r = v.u + 0x7fff + ((v.u >> 16) & 1);
    return (short)(r >> 16);
}
__device__ __forceinline__ float bf2f(unsigned short h) {
    union { unsigned u; float f; } v; v.u = ((unsigned)h) << 16;
    return v.f;
}
__device__ __forceinline__ unsigned short* u16p(float* d, size_t fofs) {
    return (unsigned short*)(d + fofs);
}
__device__ __forceinline__ const unsigned short* u16pc(const float* d, size_t fofs) {
    return (const unsigned short*)(d + fofs);
}
__device__ __forceinline__ unsigned short* w16p(float* d, int b) {
    return (b < 3) ? u16p(d, SCR_Z16F) + (size_t)b * W16_PER_B
                   : u16p(d, SCR_Z16VF);
}
__device__ __forceinline__ const unsigned short* w16pc(const float* d, int b) {
    return (b < 3) ? u16pc(d, SCR_Z16F) + (size_t)b * W16_PER_B
                   : u16pc(d, SCR_Z16VF);
}
__device__ __forceinline__ int nc_of(int TI) { return TI >= 12 ? 3 : (TI >= 6 ? 2 : 1); }
__device__ __forceinline__ int cb_of(int TI) {
    return TI < 6 ? TI : (TI < 12 ? 6 + 2 * (TI - 6) : 18 + 3 * (TI - 12));
}

// async global->LDS, 16B per lane (m97 pattern)
__device__ __forceinline__ void gll16(const unsigned short* g, short* l) {
    __builtin_amdgcn_global_load_lds(
        (const __attribute__((address_space(1))) unsigned*)g,
        (__attribute__((address_space(3))) unsigned*)l, 16, 0, 0);
}
// stage a 128x32 bf16 tile into ldsbuf[128*32] (linear); 2 issues/wave
__device__ __forceinline__ void stage_tile(const unsigned short* gbase, size_t stride_sh,
                                           short* ldsbuf, int t) {
    const int w = t >> 6, L = t & 63;
#pragma unroll
    for (int p = 0; p < 2; ++p) {
        const int r0 = w * 32 + p * 16;
        const unsigned short* src = gbase + (size_t)(r0 + (L >> 2)) * stride_sh + (L & 3) * 8;
        gll16(src, ldsbuf + r0 * 32);
    }
}
// stage a 64x32 bf16 tile into ldsbuf[64*32]; 1 issue/wave
__device__ __forceinline__ void stage64(const unsigned short* gbase, size_t stride_sh,
                                        short* ldsbuf, int t) {
    const int w = t >> 6, L = t & 63;
    const int r0 = w * 16;
    const unsigned short* src = gbase + (size_t)(r0 + (L >> 2)) * stride_sh + (L & 3) * 8;
    gll16(src, ldsbuf + r0 * 32);
}

// =====================================================================
// prep: z=0 weights -> 6 bf16 mats [d][512]; z=1 scalars + zero QN/KN/L
// (Z-tensor conversion now fused into k_qkv A-staging)
// =====================================================================
__global__ void k_prep(const float* __restrict__ Wq, const float* __restrict__ Wk,
                       const float* __restrict__ Wv, const float* __restrict__ Wp,
                       const float* __restrict__ tau, const float* __restrict__ delta,
                       const float* __restrict__ lamOm, const float* __restrict__ lamGa,
                       const float* __restrict__ lamC,
                       float* __restrict__ dout) {
    const int z = blockIdx.z;
    if (z == 0) {
        const float* Ws[4] = {Wq, Wk, Wv, Wp};
        const long n4 = 6L * 256 * 512 / 4;
        for (long e4 = (long)blockIdx.x * 256 + threadIdx.x; e4 < n4;
             e4 += (long)gridDim.x * 256) {
            const long e = e4 * 4;
            const int k = (int)(e & 511);
            const long rest = e >> 9;
            const int dd = (int)(rest & 255);
            const int m = (int)(rest >> 8);
            int proj, mode;
            if (m < 3)      { proj = m; mode = 0; }
            else if (m == 3){ proj = 2; mode = 1; }
            else            { proj = 3; mode = m - 4; }
            const int kc = k >> 8, kk = k & 255;
            int wc; float sgn;
            if (mode == 0) { wc = kc; sgn = kc ? -1.f : 1.f; }
            else           { wc = 1 - kc; sgn = 1.f; }
            float4 v = *(const float4*)&Ws[proj][((size_t)wc * DD + dd) * DD + kk];
            ushort4 o;
            o.x = (unsigned short)f2bf(sgn * v.x); o.y = (unsigned short)f2bf(sgn * v.y);
            o.z = (unsigned short)f2bf(sgn * v.z); o.w = (unsigned short)f2bf(sgn * v.w);
            unsigned short* dst = (m < 4)
                ? u16p(dout, SCR_Z16VF) + U_W16 + (size_t)m * 131072
                : u16p(dout, SCR_W16P) + (size_t)(m - 4) * 131072;
            *(ushort4*)&dst[(size_t)dd * 512 + k] = o;
        }
    } else {
        const int idx = blockIdx.x * 256 + threadIdx.x;
        if (idx < 3 * BN * NN) dout[SCR_QN + idx] = 0.f;
        if (blockIdx.x == 0) {
            __shared__ float red[8];
            const int t = threadIdx.x;
            float c2 = lamC[t] * lamC[t];
            float ga = c2 * (lamGa[t] * lamGa[t] + EPSF);
            float om = c2 * (lamOm[t] * lamOm[t] + EPSF);
            for (int o = 32; o > 0; o >>= 1) {
                ga += __shfl_down(ga, o, 64);
                om += __shfl_down(om, o, 64);
            }
            if ((t & 63) == 0) { red[t >> 6] = ga; red[4 + (t >> 6)] = om; }
            __syncthreads();
            if (t == 0) {
                float gs = red[0] + red[1] + red[2] + red[3];
                float os = red[4] + red[5] + red[6] + red[7];
                float* scal = dout + SCR_SC;
                scal[0] = tau[0] * tau[0];
                scal[1] = 1.f / (1.f + __expf(-delta[0]));
                scal[2] = gs / 256.f;
                scal[3] = os / 256.f;
            }
        }
    }
}

// =====================================================================
// QKV projection, 64x128 tiles. A-operand converted fp32->bf16 ON THE
// FLY from the original Z layout (B,2,N,D) -- no separate cvt pass.
// B-operand stays on global_load_lds from prepped W16.
// z: 0=Qr->Q16(+QN), 1=Kr->K16(+KN), 2=Vr->UVch0, 3=Vi->est ch1 + E16 ch1
// =====================================================================
__global__ __launch_bounds__(256) void k_qkv(const float* __restrict__ Zq,
                                             const float* __restrict__ Zk,
                                             const float* __restrict__ Zv,
                                             const float* __restrict__ bq,
                                             const float* __restrict__ bk,
                                             const float* __restrict__ bv,
                                             float* __restrict__ dout)
{
    __shared__ short Al[64 * 32];
    __shared__ short Bl[128 * 32];
    const int z = blockIdx.z;
    const int d0 = blockIdx.x * 128;
    const int b = blockIdx.y >> 5;
    const int n0 = (blockIdx.y & 31) * 64;

    const float* Zf = (z == 0) ? Zq : (z == 1) ? Zk : Zv;
    const unsigned short* W16 = u16pc(dout, SCR_Z16VF) + U_W16 + (size_t)z * 131072;
    const float* bias = (z == 0) ? bq : (z == 1) ? bk : bv;
    const int bofs = (z == 3) ? DD : 0;

    const int t = threadIdx.x, wave = t >> 6, lane = t & 63, quad = lane >> 4, lm = lane & 15;
    const int wr = (wave >> 1) * 32, wc = (wave & 1) * 64;
    const int ar = t >> 2, ac8 = (t & 3) * 8;       // A-staging coords
    const unsigned short* Bbase = W16 + (size_t)d0 * 512;

    f32x4 acc[2][4];
#pragma unroll
    for (int i = 0; i < 2; ++i)
#pragma unroll
        for (int j = 0; j < 4; ++j) acc[i][j] = (f32x4){0.f, 0.f, 0.f, 0.f};

    for (int kt = 0; kt < 16; ++kt) {
        const int kk0 = kt * 32;
        // A: fp32 load + convert (c = channel, dcol = col within channel)
        const int c = kt >> 3;
        const int dcol = (kt & 7) * 32;
        const float* As = Zf + ((size_t)((b * 2 + c) * NN + n0 + ar)) * DD + dcol + ac8;
        float4 av0 = *(const float4*)(As + 0);
        float4 av1 = *(const float4*)(As + 4);
        // B: async global->LDS
        stage_tile(Bbase + kk0, 512, Bl, t);
        ushort4 ha, hb;
        ha.x = (unsigned short)f2bf(av0.x); ha.y = (unsigned short)f2bf(av0.y);
        ha.z = (unsigned short)f2bf(av0.z); ha.w = (unsigned short)f2bf(av0.w);
        hb.x = (unsigned short)f2bf(av1.x); hb.y = (unsigned short)f2bf(av1.y);
        hb.z = (unsigned short)f2bf(av1.z); hb.w = (unsigned short)f2bf(av1.w);
        *(ushort4*)&Al[ar * 32 + ac8]     = ha;
        *(ushort4*)&Al[ar * 32 + ac8 + 4] = hb;
        __syncthreads();
        bf16x8 af[2], bff[4];
#pragma unroll
        for (int mi = 0; mi < 2; ++mi) af[mi] = *(const bf16x8*)&Al[(wr + mi * 16 + lm) * 32 + quad * 8];
#pragma unroll
        for (int nj = 0; nj < 4; ++nj) bff[nj] = *(const bf16x8*)&Bl[(wc + nj * 16 + lm) * 32 + quad * 8];
#pragma unroll
        for (int mi = 0; mi < 2; ++mi)
#pragma unroll
            for (int nj = 0; nj < 4; ++nj)
                acc[mi][nj] = __builtin_amdgcn_mfma_f32_16x16x32_bf16(af[mi], bff[nj], acc[mi][nj], 0, 0, 0);
        __syncthreads();
    }

    if (z <= 1) {
        unsigned short* O16 = u16p(dout, SCR_B0) + (z ? U_K16 : U_Q16) + (size_t)b * NN * DD;
        float* NRM = dout + (z ? SCR_KN : SCR_QN) + b * NN;
#pragma unroll
        for (int mi = 0; mi < 2; ++mi)
#pragma unroll
            for (int r = 0; r < 4; ++r) {
                const int m = n0 + wr + mi * 16 + quad * 4 + r;
                float ss = 0.f;
#pragma unroll
                for (int nj = 0; nj < 4; ++nj) {
                    const int d = d0 + wc + nj * 16 + lm;
                    unsigned short h = (unsigned short)f2bf(acc[mi][nj][r] + bias[d]);
                    O16[(size_t)m * DD + d] = h;
                    const float vb = bf2f(h);
                    ss = fmaf(vb, vb, ss);
                }
                ss += __shfl_down(ss, 8, 16); ss += __shfl_down(ss, 4, 16);
                ss += __shfl_down(ss, 2, 16); ss += __shfl_down(ss, 1, 16);
                if (lm == 0) atomicAdd(&NRM[m], ss);
            }
    } else if (z == 2) {
        float* UV0 = dout + OFF_UV + (size_t)(b * 2) * NN * DD;
#pragma unroll
        for (int mi = 0; mi < 2; ++mi)
#pragma unroll
            for (int r = 0; r < 4; ++r) {
                const int m = n0 + wr + mi * 16 + quad * 4 + r;
#pragma unroll
                for (int nj = 0; nj < 4; ++nj) {
                    const int d = d0 + wc + nj * 16 + lm;
                    UV0[(size_t)m * DD + d] = acc[mi][nj][r] + bias[d];
                }
            }
    } else {
        const float s1 = 1.f - dout[SCR_SC + 1];
        float* EST1 = dout + OFF_EST + (size_t)(b * 2 + 1) * NN * DD;
        unsigned short* E16 = u16p(dout, SCR_E16F) + (size_t)b * NN * 512;
#pragma unroll
        for (int mi = 0; mi < 2; ++mi)
#pragma unroll
            for (int r = 0; r < 4; ++r) {
                const int m = n0 + wr + mi * 16 + quad * 4 + r;
#pragma unroll
                for (int nj = 0; nj < 4; ++nj) {
                    const int d = d0 + wc + nj * 16 + lm;
                    const float v = s1 * (acc[mi][nj][r] + bias[bofs + d]);
                    EST1[(size_t)m * DD + d] = v;
                    E16[(size_t)m * 512 + 256 + d] = (unsigned short)f2bf(v);
                }
            }
    }
}

// =====================================================================
// output projection, 64x128 tiles; z==2 slice zeros b2/b3-imag (w16)
// + PART remainder of b1-imag, concurrently with the GEMM
// =====================================================================
__global__ __launch_bounds__(256) void k_outproj(const float* __restrict__ bp,
                                                 float* __restrict__ dout)
{
    __shared__ short Al[64 * 32];
    __shared__ short Bl[128 * 32];
    const int z = blockIdx.z;
    if (z == 2) {
        const long idx = (long)(blockIdx.y * 2 + blockIdx.x) * 256 + threadIdx.x;
        const float4 zz4 = {0.f, 0.f, 0.f, 0.f};
        for (long u = idx * 4; u < (long)NN * NN; u += 256L * 256 * 4) {
            *(float4*)&dout[SCR_Z16F + u] = zz4;
            *(float4*)&dout[SCR_Z16VF + u] = zz4;
        }
        // PART half of b1-imag (dead after blendfills; outproj reads only E16)
        for (long u = idx * 4; u < 2097152; u += 256L * 256 * 4)
            *(float4*)&dout[SCR_E16F + 2097152 + u] = zz4;
        return;
    }
    const int d0 = blockIdx.x * 128;
    const int b = blockIdx.y >> 5;
    const int n0 = (blockIdx.y & 31) * 64;
    const unsigned short* E16 = u16pc(dout, SCR_E16F) + (size_t)b * NN * 512;
    const unsigned short* W16 = u16pc(dout, SCR_W16P) + (size_t)z * 131072;

    const int t = threadIdx.x, wave = t >> 6, lane = t & 63, quad = lane >> 4, lm = lane & 15;
    const int wr = (wave >> 1) * 32, wc = (wave & 1) * 64;
    const unsigned short* Abase = E16 + (size_t)n0 * 512;
    const unsigned short* Bbase = W16 + (size_t)d0 * 512;

    f32x4 acc[2][4];
#pragma unroll
    for (int i = 0; i < 2; ++i)
#pragma unroll
        for (int j = 0; j < 4; ++j) acc[i][j] = (f32x4){0.f, 0.f, 0.f, 0.f};

    for (int kt = 0; kt < 16; ++kt) {
        const int kk0 = kt * 32;
        stage64(Abase + kk0, 512, Al, t);
        stage_tile(Bbase + kk0, 512, Bl, t);
        __syncthreads();
        bf16x8 af[2], bff[4];
#pragma unroll
        for (int mi = 0; mi < 2; ++mi) af[mi] = *(const bf16x8*)&Al[(wr + mi * 16 + lm) * 32 + quad * 8];
#pragma unroll
        for (int nj = 0; nj < 4; ++nj) bff[nj] = *(const bf16x8*)&Bl[(wc + nj * 16 + lm) * 32 + quad * 8];
#pragma unroll
        for (int mi = 0; mi < 2; ++mi)
#pragma unroll
            for (int nj = 0; nj < 4; ++nj)
                acc[mi][nj] = __builtin_amdgcn_mfma_f32_16x16x32_bf16(af[mi], bff[nj], acc[mi][nj], 0, 0, 0);
        __syncthreads();
    }
    const int bofs = z ? DD : 0;
    float* O = dout + OFF_OUT + (size_t)(b * 2 + z) * NN * DD;
#pragma unroll
    for (int mi = 0; mi < 2; ++mi)
#pragma unroll
        for (int r = 0; r < 4; ++r) {
            const int m = n0 + wr + mi * 16 + quad * 4 + r;
#pragma unroll
            for (int nj = 0; nj < 4; ++nj) {
                const int d = d0 + wc + nj * 16 + lm;
                O[(size_t)m * DD + d] = acc[mi][nj][r] + bp[bofs + d];
            }
        }
}

// =====================================================================
// causal scores, 64x128 i-half tiles (x < 272) + fused V-transpose
// (x >= 272: UV ch0 [b][n][d] fp32 -> VT16 [b][d][n] bf16)
// =====================================================================
__global__ __launch_bounds__(256) void k_scores(const float* __restrict__ tmeas,
                                                float* __restrict__ dout) {
    __shared__ __align__(16) float smemf[4160];  // 16.6KB: Al|Bl (12KB) or T[64][65]
    short* Al = (short*)smemf;
    short* Bl = ((short*)smemf) + 2048;
    const int b = blockIdx.y;
    if (blockIdx.x >= 272) {
        // ---- V transpose job ----
        float (*T)[65] = (float(*)[65])smemf;
        const int vj = blockIdx.x - 272;
        const int nb = (vj & 31) * 64, db = (vj >> 5) * 64;
        const float* V = dout + OFF_UV + (size_t)(b * 2) * NN * DD;
        unsigned short* VT = u16p(dout, SCR_B0) + U_VT16 + (size_t)b * DD * NN;
        const int tr = threadIdx.x >> 4, tc = (threadIdx.x & 15) * 4;
#pragma unroll
        for (int p = 0; p < 4; ++p) {
            float4 v = *(const float4*)&V[(size_t)(nb + tr + p * 16) * DD + db + tc];
            T[tr + p * 16][tc + 0] = v.x; T[tr + p * 16][tc + 1] = v.y;
            T[tr + p * 16][tc + 2] = v.z; T[tr + p * 16][tc + 3] = v.w;
        }
        __syncthreads();
#pragma unroll
        for (int p = 0; p < 4; ++p) {
            const int d = tr + p * 16;
            ushort4 o;
            o.x = (unsigned short)f2bf(T[tc + 0][d]);
            o.y = (unsigned short)f2bf(T[tc + 1][d]);
            o.z = (unsigned short)f2bf(T[tc + 2][d]);
            o.w = (unsigned short)f2bf(T[tc + 3][d]);
            *(ushort4*)&VT[(size_t)(db + d) * NN + nb + tc] = o;
        }
        return;
    }
    const int x2 = blockIdx.x;
    const int x = x2 >> 1, ih = x2 & 1;
    int ti = (int)((sqrtf(8.f * x + 1.f) - 1.f) * 0.5f);
    while ((ti + 1) * (ti + 2) / 2 <= x) ++ti;
    while (ti * (ti + 1) / 2 > x) --ti;
    const int tj = x - ti * (ti + 1) / 2;
    const int i0 = ti * 128, j0 = tj * 128;
    const int ib = i0 + ih * 64;
    const unsigned short* Q16 = u16pc(dout, SCR_B0) + U_Q16 + (size_t)b * NN * DD;
    const unsigned short* K16 = u16pc(dout, SCR_B0) + U_K16 + (size_t)b * NN * DD;
    const int t = threadIdx.x, wave = t >> 6, lane = t & 63, quad = lane >> 4, lm = lane & 15;
    const int wr = (wave >> 1) * 32, wc = (wave & 1) * 64;
    const unsigned short* Abase = Q16 + (size_t)ib * DD;
    const unsigned short* Bbase = K16 + (size_t)j0 * DD;

    f32x4 acc[2][4];
#pragma unroll
    for (int i = 0; i < 2; ++i)
#pragma unroll
        for (int j = 0; j < 4; ++j) acc[i][j] = (f32x4){0.f, 0.f, 0.f, 0.f};

    for (int kt = 0; kt < 8; ++kt) {
        const int kk0 = kt * 32;
        stage64(Abase + kk0, DD, Al, t);
        stage_tile(Bbase + kk0, DD, Bl, t);
        __syncthreads();
        bf16x8 af[2], bff[4];
#pragma unroll
        for (int mi = 0; mi < 2; ++mi) af[mi] = *(const bf16x8*)&Al[(wr + mi * 16 + lm) * 32 + quad * 8];
#pragma unroll
        for (int nj = 0; nj < 4; ++nj) bff[nj] = *(const bf16x8*)&Bl[(wc + nj * 16 + lm) * 32 + quad * 8];
#pragma unroll
        for (int mi = 0; mi < 2; ++mi)
#pragma unroll
            for (int nj = 0; nj < 4; ++nj)
                acc[mi][nj] = __builtin_amdgcn_mfma_f32_16x16x32_bf16(af[mi], bff[nj], acc[mi][nj], 0, 0, 0);
        __syncthreads();
    }

    const float tau2 = dout[SCR_SC + 0], ga = dout[SCR_SC + 2], om = dout[SCR_SC + 3];
    unsigned short* WT = w16p(dout, b) + (size_t)x * 16384;
    const float* QN_ = dout + SCR_QN + b * NN;
    const float* KN_ = dout + SCR_KN + b * NN;
    float kn[4], tjv[4]; int jj[4], jl[4];
#pragma unroll
    for (int nj = 0; nj < 4; ++nj) {
        jl[nj] = wc + nj * 16 + lm;
        jj[nj] = j0 + jl[nj];
        kn[nj] = KN_[jj[nj]];
        tjv[nj] = tmeas[jj[nj]];
    }
#pragma unroll
    for (int mi = 0; mi < 2; ++mi)
#pragma unroll
        for (int r = 0; r < 4; ++r) {
            const int li = ih * 64 + wr + mi * 16 + quad * 4 + r;
            const int i = i0 + li;
            const float qni = QN_[i], tqi = tmeas[i];
            float rs = 0.f;
#pragma unroll
            for (int nj = 0; nj < 4; ++nj) {
                float xx = ga + om * fabsf(tqi - tjv[nj]) + qni + kn[nj] - 2.f * acc[mi][nj][r];
                xx = fmaxf(xx, 1e-30f);
                float w = (tau2 == 1.f) ? __builtin_amdgcn_rcpf(xx)
                                        : __expf(-tau2 * __logf(xx));
                if (jj[nj] > i) w = 0.f;
                const unsigned short h = (unsigned short)f2bf(w);
                WT[(size_t)li * 128 + jl[nj]] = h;
                rs += bf2f(h);
            }
            rs += __shfl_down(rs, 8, 16); rs += __shfl_down(rs, 4, 16);
            rs += __shfl_down(rs, 2, 16); rs += __shfl_down(rs, 1, 16);
            if (lm == 0) atomicAdd(&dout[SCR_L + b * NN + i], rs);
        }
}

// =====================================================================
// est_inner: 128x64 tiles (d-quarters, acc[4][2]) -> 480 blocks
// A = raw bf16 w16 (norm deferred), B = V^T; partials -> PART
// =====================================================================
__global__ __launch_bounds__(256) void k_estinner(float* __restrict__ dout) {
    __shared__ short Al[128 * 32];
    __shared__ short Bl[64 * 32];
    const int b = blockIdx.y;
    const int chunk = blockIdx.x >> 2, qd = blockIdx.x & 3;
    int y = chunk, TI = 0, cb = 0;
    for (;;) { const int nc = nc_of(TI); if (y < nc) break; y -= nc; cb += nc; ++TI; }
    const int kbeg = y * 768;
    const int kend = min(kbeg + 768, (TI + 1) * 128);
    const int nst = (kend - kbeg) >> 5;
    const int cidx = cb + y;
    const int tri = TI * (TI + 1) / 2;
    const unsigned short* WT = w16pc(dout, b);
    const unsigned short* VT = u16pc(dout, SCR_B0) + U_VT16 + (size_t)b * DD * NN
                             + (size_t)(qd * 64) * NN;

    const int t = threadIdx.x, wave = t >> 6, lane = t & 63, quad = lane >> 4, lm = lane & 15;
    const int rh = (wave >> 1) * 64, ch = (wave & 1) * 32;

    f32x4 acc[4][2];
#pragma unroll
    for (int i = 0; i < 4; ++i)
#pragma unroll
        for (int j = 0; j < 2; ++j) acc[i][j] = (f32x4){0.f, 0.f, 0.f, 0.f};

    for (int kt = 0; kt < nst; ++kt) {
        const int kk0 = kbeg + kt * 32;
        const int tile = kk0 >> 7;
        stage_tile(WT + (size_t)(tri + tile) * 16384 + (kk0 & 127), 128, Al, t);
        stage64(VT + kk0, NN, Bl, t);
        __syncthreads();
        bf16x8 af[4], bff[2];
#pragma unroll
        for (int mi = 0; mi < 4; ++mi) af[mi] = *(const bf16x8*)&Al[(rh + mi * 16 + lm) * 32 + quad * 8];
#pragma unroll
        for (int nj = 0; nj < 2; ++nj) bff[nj] = *(const bf16x8*)&Bl[(ch + nj * 16 + lm) * 32 + quad * 8];
#pragma unroll
        for (int mi = 0; mi < 4; ++mi)
#pragma unroll
            for (int nj = 0; nj < 2; ++nj)
                acc[mi][nj] = __builtin_amdgcn_mfma_f32_16x16x32_bf16(af[mi], bff[nj], acc[mi][nj], 0, 0, 0);
        __syncthreads();
    }
    unsigned short* P = u16p(dout, SCR_E16F) + U_PART +
                        ((size_t)(b * 30 + cidx)) * 128 * 256;
#pragma unroll
    for (int mi = 0; mi < 4; ++mi)
#pragma unroll
        for (int r = 0; r < 4; ++r) {
            const int ri = rh + mi * 16 + quad * 4 + r;
#pragma unroll
            for (int nj = 0; nj < 2; ++nj) {
                const int d = qd * 64 + ch + nj * 16 + lm;
                P[(size_t)ri * 256 + d] = (unsigned short)f2bf(acc[mi][nj][r]);
            }
        }
}

// =====================================================================
// fused blend + Qij writer + structural fills. grid (2048, 1, 16).
// =====================================================================
__global__ void k_blendfills(float* __restrict__ dout) {
    const int z = blockIdx.z;
    if (z < 4) {
        const int b = z;
        if (blockIdx.x >= 512) return;
        const int t = threadIdx.x;
        const int i = blockIdx.x * 4 + (t >> 6);
        const int d4 = (t & 63) * 4;
        const int TI = i >> 7;
        const int nc = nc_of(TI), cb = cb_of(TI);
        const float s = dout[SCR_SC + 1];
        const float linv = 1.f / dout[SCR_L + b * NN + i];
        const unsigned short* P = u16pc(dout, SCR_E16F) + U_PART;
        float4 sum = {0.f, 0.f, 0.f, 0.f};
        for (int c = 0; c < nc; ++c) {
            ushort4 pv = *(const ushort4*)&P[((size_t)(b * 30 + cb + c) * 128 + (i & 127)) * 256 + d4];
            sum.x += bf2f(pv.x); sum.y += bf2f(pv.y);
            sum.z += bf2f(pv.z); sum.w += bf2f(pv.w);
        }
        const float4 vr = *(const float4*)&dout[OFF_UV + ((size_t)(b * 2) * NN + i) * DD + d4];
        const float sl = s * linv;
        float4 ev;
        ev.x = (1.f - s) * vr.x + sl * sum.x;
        ev.y = (1.f - s) * vr.y + sl * sum.y;
        ev.z = (1.f - s) * vr.z + sl * sum.z;
        ev.w = (1.f - s) * vr.w + sl * sum.w;
        *(float4*)&dout[OFF_EST + ((size_t)(b * 2) * NN + i) * DD + d4] = ev;
        ushort4 o;
        o.x = (unsigned short)f2bf(ev.x); o.y = (unsigned short)f2bf(ev.y);
        o.z = (unsigned short)f2bf(ev.z); o.w = (unsigned short)f2bf(ev.w);
        *(ushort4*)&u16p(dout, SCR_E16F)[((size_t)(b * NN + i)) * 512 + d4] = o;
        return;
    }
    if (z < 8) {
        const int b = z - 4, i = blockIdx.x;
        const int TI = i >> 7, li = i & 127;
        const int tri = TI * (TI + 1) / 2;
        const float linv = 1.f / dout[SCR_L + b * NN + i];
        const unsigned short* WTb = w16pc(dout, b);
        float* row = dout + OFF_QIJ + (size_t)b * 2 * NN * NN + (size_t)i * NN;
        for (int j4 = threadIdx.x * 4; j4 < NN; j4 += 1024) {
            const int tj = j4 >> 7;
            float4 o = {0.f, 0.f, 0.f, 0.f};
            if (tj <= TI) {
                ushort4 h = *(const ushort4*)&WTb[((size_t)(tri + tj)) * 16384
                                                  + (size_t)li * 128 + (j4 & 127)];
                o.x = bf2f(h.x) * linv; o.y = bf2f(h.y) * linv;
                o.z = bf2f(h.z) * linv; o.w = bf2f(h.w) * linv;
            }
            *(float4*)&row[j4] = o;
        }
        return;
    }
    size_t base; long n; float val = 0.f;
    if (z == 8)       { base = SCR_B0; n = 3145728; }
    else if (z == 9)  { base = OFF_VV; n = (long)NN * DD; val = 1.f; }
    else if (z == 10) { base = OFF_VV + (size_t)NN * DD; n = (long)NN * DD; }
    else if (z < 15)  { base = OFF_UV + (size_t)(2 * (z - 11) + 1) * NN * DD; n = (long)NN * DD; }
    else              { base = OFF_LH; n = 512; }
    float* p = dout + base;
    const float4 v = {val, val, val, val};
    for (long i = ((long)blockIdx.x * 256 + threadIdx.x) * 4; i < n;
         i += (long)gridDim.x * 1024)
        *(float4*)&p[i] = v;
}

// zero E16 half of b1-imag + b0 tail (QN/KN/L/SC/W16P) after outproj
__global__ void k_tail(float* __restrict__ dout) {
    const float4 zz = {0.f, 0.f, 0.f, 0.f};
    const long n1 = 2097152;  // E16: BN*NN*512 ushorts
    for (long i = ((long)blockIdx.x * 256 + threadIdx.x) * 4; i < n1;
         i += (long)gridDim.x * 1024)
        *(float4*)&dout[SCR_E16F + i] = zz;
    const long n0 = (long)NN * NN - 3145728;  // 1048576 floats
    for (long i = ((long)blockIdx.x * 256 + threadIdx.x) * 4; i < n0;
         i += (long)gridDim.x * 1024)
        *(float4*)&dout[SCR_QN + i] = zz;
}

extern "C" void kernel_launch(void* const* d_in, const int* in_sizes, int n_in,
                              void* d_out, int out_size, void* d_ws, size_t ws_size,
                              hipStream_t stream) {
    const float* Zq = (const float*)d_in[0];
    const float* Zk = (const float*)d_in[1];
    const float* Zv = (const float*)d_in[2];
    const float* tm = (const float*)d_in[3];
    const float* Wq = (const float*)d_in[4];
    const float* bq = (const float*)d_in[5];
    const float* Wk = (const float*)d_in[6];
    const float* bk = (const float*)d_in[7];
    const float* Wv = (const float*)d_in[8];
    const float* bv = (const float*)d_in[9];
    const float* Wp = (const float*)d_in[10];
    const float* bp = (const float*)d_in[11];
    const float* lamOm = (const float*)d_in[13];
    const float* lamGa = (const float*)d_in[14];
    const float* tau = (const float*)d_in[15];
    const float* delta = (const float*)d_in[16];
    const float* lamC = (const float*)d_in[17];
    float* out = (float*)d_out;

    k_prep<<<dim3(256, 1, 2), dim3(256), 0, stream>>>(
        Wq, Wk, Wv, Wp, tau, delta, lamOm, lamGa, lamC, out);
    k_qkv<<<dim3(2, 128, 4), dim3(256), 0, stream>>>(Zq, Zk, Zv, bq, bk, bv, out);
    k_scores<<<dim3(400, 4), dim3(256), 0, stream>>>(tm, out);   // + fused vtrans
    k_estinner<<<dim3(120, 4), dim3(256), 0, stream>>>(out);
    k_blendfills<<<dim3(2048, 1, 16), dim3(256), 0, stream>>>(out);
    k_outproj<<<dim3(2, 128, 3), dim3(256), 0, stream>>>(bp, out); // + w16/PART zero
    k_tail<<<dim3(512), dim3(256), 0, stream>>>(out);
}